// Round 2
// baseline (141.733 us; speedup 1.0000x reference)
//
#include <hip/hip_runtime.h>

// MomentConv2d: B=32, CIN=16, COUT=32, H=W=14, K=5, S=2 -> OH=OW=5
// out = (mean [32,32,5,5], cov [32,32,5,5,5,5]) concatenated, f32.
//
// cov[b,i,p,q,r,s] = sum_c sum_{a,bb,cc,d} w[i,a,bb] w[i,cc,d]
//                    * C[b,c, 2p+a, 2q+bb, 2r+cc, 2s+d]
// Round 2 design:
//   k1: CS[b,h1,w1,h2,w2] = sum_c C[b,c,...]   (pure streaming reduction,
//       78.7->4.9 MB; skip h1=13, never used downstream)
//   k2: per (b,i) block: both separable 5x5 convs from L2-hot CS[b].

#define NB   32
#define NCIN 16
#define NCO  32
#define HH   14
#define HW   196        // 14*14
#define CS_B 9604       // 38416/4 float4 per b
#define CS_B13 8918     // 13*686 float4 (h1 = 0..12 only)

// CS[b][h1][w1][h2][w2], 4.9 MB static scratch (h1=13 slice left unwritten)
__device__ float g_CS[NB * 38416];

// ---------------------------------------------------------------------------
// Kernel 1: streaming cin-reduction. grid (35, 32), 256 threads.
// ---------------------------------------------------------------------------
__global__ __launch_bounds__(256) void k1_cs(const float* __restrict__ C) {
  const int b    = blockIdx.y;
  const int idx4 = blockIdx.x * 256 + threadIdx.x;
  if (idx4 >= CS_B13) return;                       // h1=13 never needed
  const float4* C4 = (const float4*)C;
  float4* CS4 = (float4*)g_CS;
  const int base = (b * NCIN) * CS_B + idx4;
  float4 acc = make_float4(0.f, 0.f, 0.f, 0.f);
  #pragma unroll
  for (int c = 0; c < NCIN; ++c) {
    float4 v = C4[base + c * CS_B];
    acc.x += v.x; acc.y += v.y; acc.z += v.z; acc.w += v.w;
  }
  CS4[b * CS_B + idx4] = acc;
}

// ---------------------------------------------------------------------------
// Kernel 2: blocks 0..1023 -> cov for (b,i); blocks 1024..1055 -> mean for b.
// 256 threads.
// ---------------------------------------------------------------------------
__global__ __launch_bounds__(256) void k2_out(const float* __restrict__ u,
                                              const float* __restrict__ w,
                                              float* __restrict__ out) {
  const int blk = blockIdx.x;
  const int tid = threadIdx.x;

  if (blk < NB * NCO) {
    const int b = blk >> 5;
    const int i = blk & 31;

    __shared__ float slab[2744];   // CS[b,h1,:,:,:] for current h1 (11 KB)
    __shared__ float T1[4900];     // [h1][w1][rs], h1<=12,w1<=12 used (19.6 KB)

    float wr[25];
    #pragma unroll
    for (int t = 0; t < 25; ++t) wr[t] = w[i * 25 + t];   // uniform -> sgpr

    const float4* CS4 = (const float4*)g_CS;
    float4* slab4 = (float4*)slab;

    // ---- conv over second index pair (h2,w2) -> rs, per h1 row ----
    for (int h1 = 0; h1 < 13; ++h1) {
      __syncthreads();
      for (int j = tid; j < 686; j += 256)
        slab4[j] = CS4[b * CS_B + h1 * 686 + j];
      __syncthreads();
      for (int o = tid; o < 325; o += 256) {        // w1 0..12, rs 0..24
        const int w1 = o / 25;
        const int rs = o % 25;
        const int r = rs / 5, s = rs % 5;
        const float* p0 = slab + w1 * 196 + (2 * r) * 14 + 2 * s;
        float acc = 0.f;
        #pragma unroll
        for (int cc = 0; cc < 5; ++cc) {
          #pragma unroll
          for (int d = 0; d < 5; ++d)
            acc += wr[cc * 5 + d] * p0[cc * 14 + d];
        }
        T1[h1 * 350 + w1 * 25 + rs] = acc;
      }
    }
    __syncthreads();

    // ---- conv over first index pair (h1,w1) -> (p,q) ----
    for (int o = tid; o < 625; o += 256) {          // o = ((p*5+q)*5+r)*5+s
      const int p  = o / 125;
      const int q  = (o / 25) % 5;
      const int rs = o % 25;
      float acc = 0.f;
      #pragma unroll
      for (int a = 0; a < 5; ++a) {
        #pragma unroll
        for (int bb = 0; bb < 5; ++bb)
          acc += wr[a * 5 + bb] * T1[(2 * p + a) * 350 + (2 * q + bb) * 25 + rs];
      }
      out[25600 + blk * 625 + o] = acc;
    }
  } else {
    // ---- mean path ----
    const int b = blk - NB * NCO;
    __shared__ float us[HW];
    for (int j = tid; j < HW; j += 256) {
      float acc = 0.f;
      #pragma unroll
      for (int c = 0; c < NCIN; ++c) acc += u[(b * NCIN + c) * HW + j];
      us[j] = acc;
    }
    __syncthreads();
    for (int o = tid; o < NCO * 25; o += 256) {     // o = i*25 + p*5 + q
      const int i = o / 25;
      const int p = (o / 5) % 5;
      const int q = o % 5;
      float acc = 0.f;
      #pragma unroll
      for (int a = 0; a < 5; ++a) {
        #pragma unroll
        for (int bb = 0; bb < 5; ++bb)
          acc += w[i * 25 + a * 5 + bb] * us[(2 * p + a) * 14 + 2 * q + bb];
      }
      out[b * 800 + o] = acc;
    }
  }
}

extern "C" void kernel_launch(void* const* d_in, const int* in_sizes, int n_in,
                              void* d_out, int out_size, void* d_ws, size_t ws_size,
                              hipStream_t stream) {
  const float* u = (const float*)d_in[0];   // [32,16,14,14]
  const float* C = (const float*)d_in[1];   // [32,16,14,14,14,14]
  const float* w = (const float*)d_in[2];   // [32,1,5,5]
  float* out = (float*)d_out;               // 25600 mean + 640000 cov, f32

  hipLaunchKernelGGL(k1_cs, dim3(35, 32), dim3(256), 0, stream, C);
  hipLaunchKernelGGL(k2_out, dim3(NB * NCO + NB), dim3(256), 0, stream, u, w, out);
}